// Round 4
// baseline (53.751 us; speedup 1.0000x reference)
//
#include <hip/hip_runtime.h>

// TT-embedding: voc_quant (32,32,32), emb_quant (8,8,16), ranks (1,8,8,1).
// out[n, e0*128+e1*16+e2] = sum_{r1,r2} c0[i0][e0][r1]*c1[i1][r1][e1][r2]*c2[i2][r2][e2]
//
// Stage 1: A[i0*32+i1][pair*8+r2] = sum_r1 c0*c1  (2 MB, L2-resident).
// Stage 2: c2 (16 KB) staged in LDS once per block; G=16 indices per block.
//   R2/R3 lesson: lane-duplicated global reads of c2 (16x dup) saturated L1
//   (~64 B/cyc/CU); LDS broadcast serves them conflict-free.

#define TT_A_BYTES (1024u * 512u * 4u)
#define TT_G 16

// ---- Kernel 1: A[i0][i1][pair][r2] = sum_r1 c0[i0][e0][r1] * c1[i1][r1][e1][r2]
__global__ __launch_bounds__(256) void tt_precomp_kernel(
    const float* __restrict__ c0,   // [32][8][8]
    const float* __restrict__ c1,   // [32][8][8][8]
    float* __restrict__ A)          // [1024][512]
{
    __shared__ float s0[64];
    __shared__ float s1[512];
    const int i0 = blockIdx.x >> 5;
    const int i1 = blockIdx.x & 31;
    const int t  = threadIdx.x;

    if (t < 16)
        *reinterpret_cast<float4*>(s0 + t * 4) =
            *reinterpret_cast<const float4*>(c0 + i0 * 64 + t * 4);
    if (t < 128)
        *reinterpret_cast<float4*>(s1 + t * 4) =
            *reinterpret_cast<const float4*>(c1 + i1 * 512 + t * 4);
    __syncthreads();

    float* Ar = A + (size_t)blockIdx.x * 512;
    #pragma unroll
    for (int v = t; v < 512; v += 256) {
        const int pair = v >> 3;            // e0*8 + e1
        const int r2   = v & 7;
        const int e0   = pair >> 3;
        const int e1   = pair & 7;
        float acc = 0.f;
        #pragma unroll
        for (int r1 = 0; r1 < 8; ++r1)
            acc = fmaf(s0[e0 * 8 + r1], s1[r1 * 64 + e1 * 8 + r2], acc);
        Ar[v] = acc;
    }
}

// ---- Kernel 2: out[n][pair*16 + e2] = sum_r2 A[flat>>5][pair][r2] * c2[i2][r2][e2]
// c2 lives in LDS (staged once); A read from global (L1/L2); no loop barriers.
__global__ __launch_bounds__(256) void tt_emb_kernel(
    const int* __restrict__ x,
    const float* __restrict__ A,    // [1024][512]
    const float* __restrict__ c2,   // [32][8][16] = 4096 floats
    float* __restrict__ out,        // [N][1024]
    int N)
{
    __shared__ float s2[4096];      // 16 KB
    const int t = threadIdx.x;

    // stage all of c2 into LDS: 1024 float4s over 256 threads
    #pragma unroll
    for (int i = 0; i < 4; ++i)
        *reinterpret_cast<float4*>(s2 + (i * 256 + t) * 4) =
            *reinterpret_cast<const float4*>(c2 + (i * 256 + t) * 4);
    __syncthreads();

    const int nbase = blockIdx.x * TT_G;
    const int pair = t >> 2;        // 0..63
    const int e2b  = (t & 3) << 2;  // 0,4,8,12

    #pragma unroll 2
    for (int g = 0; g < TT_G; ++g) {
        const int n = nbase + g;
        if (n >= N) break;
        const int flat = x[n];                       // uniform (scalar) load
        const float* Ar  = A + (size_t)((flat >> 5) & 1023) * 512;  // i0*32+i1
        const float* c2s = s2 + (flat & 31) * 128;                  // i2 row

        const float4 tlo = *reinterpret_cast<const float4*>(Ar + pair * 8);
        const float4 thi = *reinterpret_cast<const float4*>(Ar + pair * 8 + 4);
        const float tmp[8] = {tlo.x, tlo.y, tlo.z, tlo.w, thi.x, thi.y, thi.z, thi.w};

        float r0 = 0.f, r1v = 0.f, r2v = 0.f, r3 = 0.f;
        #pragma unroll
        for (int r = 0; r < 8; ++r) {
            const float4 cv = *reinterpret_cast<const float4*>(c2s + r * 16 + e2b);
            r0  = fmaf(tmp[r], cv.x, r0);
            r1v = fmaf(tmp[r], cv.y, r1v);
            r2v = fmaf(tmp[r], cv.z, r2v);
            r3  = fmaf(tmp[r], cv.w, r3);
        }

        if (flat == 0) { r0 = r1v = r2v = r3 = 0.f; }   // padding_idx

        *reinterpret_cast<float4*>(out + (size_t)n * 1024 + (size_t)t * 4) =
            make_float4(r0, r1v, r2v, r3);
    }
}

// ---- Fallback (ws too small): round-1 LDS kernel, known-good at 39.5 us
__global__ __launch_bounds__(256) void tt_emb_lds_kernel(
    const int* __restrict__ x,
    const float* __restrict__ c0,
    const float* __restrict__ c1,
    const float* __restrict__ c2,
    float* __restrict__ out)
{
    const int n = blockIdx.x;
    const int t = threadIdx.x;

    __shared__ float s0[64];
    __shared__ float s1[512];
    __shared__ float s2[128];

    const int flat = x[n];
    const int i0 = (flat >> 10) & 31;
    const int i1 = (flat >> 5) & 31;
    const int i2 = flat & 31;

    if (t < 64)  s0[t] = c0[i0 * 64 + t];
    s1[t]        = c1[i1 * 512 + t];
    s1[t + 256]  = c1[i1 * 512 + 256 + t];
    if (t < 128) s2[t] = c2[i2 * 128 + t];
    __syncthreads();

    const int e0  = t >> 5;
    const int e1  = (t >> 2) & 7;
    const int e2b = (t & 3) << 2;

    float tmp[8] = {0.f, 0.f, 0.f, 0.f, 0.f, 0.f, 0.f, 0.f};
    #pragma unroll
    for (int r1 = 0; r1 < 8; ++r1) {
        const float a = s0[e0 * 8 + r1];
        #pragma unroll
        for (int r2 = 0; r2 < 8; ++r2)
            tmp[r2] = fmaf(a, s1[r1 * 64 + e1 * 8 + r2], tmp[r2]);
    }

    float res[4];
    #pragma unroll
    for (int q = 0; q < 4; ++q) {
        float acc = 0.f;
        #pragma unroll
        for (int r2 = 0; r2 < 8; ++r2)
            acc = fmaf(tmp[r2], s2[r2 * 16 + e2b + q], acc);
        res[q] = acc;
    }

    if (flat == 0) { res[0] = res[1] = res[2] = res[3] = 0.f; }

    *reinterpret_cast<float4*>(out + (size_t)n * 1024 + (size_t)t * 4) =
        make_float4(res[0], res[1], res[2], res[3]);
}

extern "C" void kernel_launch(void* const* d_in, const int* in_sizes, int n_in,
                              void* d_out, int out_size, void* d_ws, size_t ws_size,
                              hipStream_t stream) {
    const int*   x  = (const int*)d_in[0];     // 32768 indices
    const float* c0 = (const float*)d_in[1];   // 2048 floats
    const float* c1 = (const float*)d_in[2];   // 16384 floats
    const float* c2 = (const float*)d_in[3];   // 4096 floats
    float* out = (float*)d_out;                // 33554432 fp32

    const int N = in_sizes[0];                 // 32768

    if (ws_size >= TT_A_BYTES && (N % TT_G) == 0) {
        float* A = (float*)d_ws;
        tt_precomp_kernel<<<1024, 256, 0, stream>>>(c0, c1, A);
        tt_emb_kernel<<<N / TT_G, 256, 0, stream>>>(x, A, c2, out, N);
    } else {
        tt_emb_lds_kernel<<<N, 256, 0, stream>>>(x, c0, c1, c2, out);
    }
}

// Round 5
// 38.103 us; speedup vs baseline: 1.4107x; 1.4107x over previous
//
#include <hip/hip_runtime.h>

// TT-embedding: voc_quant (32,32,32), emb_quant (8,8,16), ranks (1,8,8,1).
// out[n, pair*16+e2] = sum_r2 A[i0*32+i1][pair*8+r2] * c2[i2][r2*16+e2],
// where A = precomputed first contraction (2 MB, L2-resident).
//
// R2-R4 lesson: all mappings with 4 lanes/pair cost ~26-32 wave-b128 per
// index; invariant ~40 us. New mapping: ONE WAVE per index, lane owns
// 4 pairs x 4 e2 -> 8 b128 A (global) + 8 b128 c2 (LDS broadcast) per
// lane-index = 16 wave-instrs/index. Everything models under the 20.6 us
// HBM store floor.

#define TT_A_BYTES (1024u * 512u * 4u)
#define TT_G 16   // indices per block; 4 per wave

// ---- Kernel 1: A[i0][i1][pair][r2] = sum_r1 c0[i0][e0][r1] * c1[i1][r1][e1][r2]
__global__ __launch_bounds__(256) void tt_precomp_kernel(
    const float* __restrict__ c0,   // [32][8][8]
    const float* __restrict__ c1,   // [32][8][8][8]
    float* __restrict__ A)          // [1024][512]
{
    __shared__ float s0[64];
    __shared__ float s1[512];
    const int i0 = blockIdx.x >> 5;
    const int i1 = blockIdx.x & 31;
    const int t  = threadIdx.x;

    if (t < 16)
        *reinterpret_cast<float4*>(s0 + t * 4) =
            *reinterpret_cast<const float4*>(c0 + i0 * 64 + t * 4);
    if (t < 128)
        *reinterpret_cast<float4*>(s1 + t * 4) =
            *reinterpret_cast<const float4*>(c1 + i1 * 512 + t * 4);
    __syncthreads();

    float* Ar = A + (size_t)blockIdx.x * 512;
    #pragma unroll
    for (int v = t; v < 512; v += 256) {
        const int pair = v >> 3;            // e0*8 + e1
        const int r2   = v & 7;
        const int e0   = pair >> 3;
        const int e1   = pair & 7;
        float acc = 0.f;
        #pragma unroll
        for (int r1 = 0; r1 < 8; ++r1)
            acc = fmaf(s0[e0 * 8 + r1], s1[r1 * 64 + e1 * 8 + r2], acc);
        Ar[v] = acc;
    }
}

// ---- Kernel 2: one wave per index; lane owns pairs [4*(l>>2), +4), e2 group l&3.
__global__ __launch_bounds__(256) void tt_emb_kernel(
    const int* __restrict__ x,
    const float* __restrict__ A,    // [1024][512]
    const float* __restrict__ c2,   // [32][8][16] = 4096 floats
    float* __restrict__ out,        // [N][1024]
    int N)
{
    __shared__ float s2[4096];      // all of c2, 16 KB
    const int t = threadIdx.x;

    #pragma unroll
    for (int i = 0; i < 4; ++i)
        *reinterpret_cast<float4*>(s2 + (i * 256 + t) * 4) =
            *reinterpret_cast<const float4*>(c2 + (i * 256 + t) * 4);
    __syncthreads();

    const int w = t >> 6;               // wave id 0..3
    const int l = t & 63;               // lane
    const int pbase = (l >> 2) << 2;    // first of this lane's 4 pairs
    const int eg    = l & 3;            // e2 group (e2 = 4*eg .. +4)
    const int nbase = blockIdx.x * TT_G + w * (TT_G / 4);

    #pragma unroll 1
    for (int g = 0; g < TT_G / 4; ++g) {
        const int n = nbase + g;
        if (n >= N) break;
        const int flat = x[n];                                   // wave-uniform
        const float* Ar  = A + (size_t)((flat >> 5) & 1023) * 512;
        const float* c2s = s2 + (flat & 31) * 128;

        // A fragments: 4 pairs x 8 r2  (coalesced-ish global, L2-resident)
        float4 alo[4], ahi[4];
        #pragma unroll
        for (int p = 0; p < 4; ++p) {
            alo[p] = *reinterpret_cast<const float4*>(Ar + (pbase + p) * 8);
            ahi[p] = *reinterpret_cast<const float4*>(Ar + (pbase + p) * 8 + 4);
        }

        float4 o[4];
        #pragma unroll
        for (int p = 0; p < 4; ++p) o[p] = make_float4(0.f, 0.f, 0.f, 0.f);

        // c2 column block: 8 x float4 LDS broadcast reads (4 distinct addrs)
        #pragma unroll
        for (int r2 = 0; r2 < 4; ++r2) {
            const float4 cv = *reinterpret_cast<const float4*>(c2s + r2 * 16 + eg * 4);
            #pragma unroll
            for (int p = 0; p < 4; ++p) {
                const float a = (r2 == 0) ? alo[p].x : (r2 == 1) ? alo[p].y
                              : (r2 == 2) ? alo[p].z : alo[p].w;
                o[p].x = fmaf(a, cv.x, o[p].x);
                o[p].y = fmaf(a, cv.y, o[p].y);
                o[p].z = fmaf(a, cv.z, o[p].z);
                o[p].w = fmaf(a, cv.w, o[p].w);
            }
        }
        #pragma unroll
        for (int r2 = 0; r2 < 4; ++r2) {
            const float4 cv = *reinterpret_cast<const float4*>(c2s + (r2 + 4) * 16 + eg * 4);
            #pragma unroll
            for (int p = 0; p < 4; ++p) {
                const float a = (r2 == 0) ? ahi[p].x : (r2 == 1) ? ahi[p].y
                              : (r2 == 2) ? ahi[p].z : ahi[p].w;
                o[p].x = fmaf(a, cv.x, o[p].x);
                o[p].y = fmaf(a, cv.y, o[p].y);
                o[p].z = fmaf(a, cv.z, o[p].z);
                o[p].w = fmaf(a, cv.w, o[p].w);
            }
        }

        if (flat == 0) {                                        // padding_idx
            #pragma unroll
            for (int p = 0; p < 4; ++p) o[p] = make_float4(0.f, 0.f, 0.f, 0.f);
        }

        // store: f4 index = pair*4 + eg -> 64B contiguous per 4-lane cluster
        float4* outp = reinterpret_cast<float4*>(out + (size_t)n * 1024);
        #pragma unroll
        for (int p = 0; p < 4; ++p)
            outp[(pbase + p) * 4 + eg] = o[p];
    }
}

// ---- Fallback (ws too small): round-1 LDS kernel, known-good at 39.5 us
__global__ __launch_bounds__(256) void tt_emb_lds_kernel(
    const int* __restrict__ x,
    const float* __restrict__ c0,
    const float* __restrict__ c1,
    const float* __restrict__ c2,
    float* __restrict__ out)
{
    const int n = blockIdx.x;
    const int t = threadIdx.x;

    __shared__ float s0[64];
    __shared__ float s1[512];
    __shared__ float s2[128];

    const int flat = x[n];
    const int i0 = (flat >> 10) & 31;
    const int i1 = (flat >> 5) & 31;
    const int i2 = flat & 31;

    if (t < 64)  s0[t] = c0[i0 * 64 + t];
    s1[t]        = c1[i1 * 512 + t];
    s1[t + 256]  = c1[i1 * 512 + 256 + t];
    if (t < 128) s2[t] = c2[i2 * 128 + t];
    __syncthreads();

    const int e0  = t >> 5;
    const int e1  = (t >> 2) & 7;
    const int e2b = (t & 3) << 2;

    float tmp[8] = {0.f, 0.f, 0.f, 0.f, 0.f, 0.f, 0.f, 0.f};
    #pragma unroll
    for (int r1 = 0; r1 < 8; ++r1) {
        const float a = s0[e0 * 8 + r1];
        #pragma unroll
        for (int r2 = 0; r2 < 8; ++r2)
            tmp[r2] = fmaf(a, s1[r1 * 64 + e1 * 8 + r2], tmp[r2]);
    }

    float res[4];
    #pragma unroll
    for (int q = 0; q < 4; ++q) {
        float acc = 0.f;
        #pragma unroll
        for (int r2 = 0; r2 < 8; ++r2)
            acc = fmaf(tmp[r2], s2[r2 * 16 + e2b + q], acc);
        res[q] = acc;
    }

    if (flat == 0) { res[0] = res[1] = res[2] = res[3] = 0.f; }

    *reinterpret_cast<float4*>(out + (size_t)n * 1024 + (size_t)t * 4) =
        make_float4(res[0], res[1], res[2], res[3]);
}

extern "C" void kernel_launch(void* const* d_in, const int* in_sizes, int n_in,
                              void* d_out, int out_size, void* d_ws, size_t ws_size,
                              hipStream_t stream) {
    const int*   x  = (const int*)d_in[0];     // 32768 indices
    const float* c0 = (const float*)d_in[1];   // 2048 floats
    const float* c1 = (const float*)d_in[2];   // 16384 floats
    const float* c2 = (const float*)d_in[3];   // 4096 floats
    float* out = (float*)d_out;                // 33554432 fp32

    const int N = in_sizes[0];                 // 32768

    if (ws_size >= TT_A_BYTES && (N % TT_G) == 0) {
        float* A = (float*)d_ws;
        tt_precomp_kernel<<<1024, 256, 0, stream>>>(c0, c1, A);
        tt_emb_kernel<<<N / TT_G, 256, 0, stream>>>(x, A, c2, out, N);
    } else {
        tt_emb_lds_kernel<<<N, 256, 0, stream>>>(x, c0, c1, c2, out);
    }
}

// Round 6
// 37.290 us; speedup vs baseline: 1.4414x; 1.0218x over previous
//
#include <hip/hip_runtime.h>

// TT-embedding: voc_quant (32,32,32), emb_quant (8,8,16), ranks (1,8,8,1).
// out[n, pair*16+e2] = sum_r2 A[i0*32+i1][pair*8+r2] * c2[i2][r2*16+e2],
// where A = precomputed first contraction (2 MB, L2-resident).
//
// R5 lesson: one wave per index (16 wave-instrs/idx) got 53.5 -> 38.1 us.
// R6 change: contiguous stores. Lane owns pairs {(l>>2)+16k}, e2grp l&3, so
// store k writes f4[l + 64k] -> four fully-contiguous 1 KB wave stores per
// index (was 16 x 64B chunks with 192B gaps -> half-covered 128B L2 sectors).
// c2 slice is invariant across k (hoisted); wave's 4 indices prefetched as int4.

#define TT_A_BYTES (1024u * 512u * 4u)
#define TT_G 16   // indices per block; 4 per wave

// ---- Kernel 1: A[i0][i1][pair][r2] = sum_r1 c0[i0][e0][r1] * c1[i1][r1][e1][r2]
__global__ __launch_bounds__(256) void tt_precomp_kernel(
    const float* __restrict__ c0,   // [32][8][8]
    const float* __restrict__ c1,   // [32][8][8][8]
    float* __restrict__ A)          // [1024][512]
{
    __shared__ float s0[64];
    __shared__ float s1[512];
    const int i0 = blockIdx.x >> 5;
    const int i1 = blockIdx.x & 31;
    const int t  = threadIdx.x;

    if (t < 16)
        *reinterpret_cast<float4*>(s0 + t * 4) =
            *reinterpret_cast<const float4*>(c0 + i0 * 64 + t * 4);
    if (t < 128)
        *reinterpret_cast<float4*>(s1 + t * 4) =
            *reinterpret_cast<const float4*>(c1 + i1 * 512 + t * 4);
    __syncthreads();

    float* Ar = A + (size_t)blockIdx.x * 512;
    #pragma unroll
    for (int v = t; v < 512; v += 256) {
        const int pair = v >> 3;            // e0*8 + e1
        const int r2   = v & 7;
        const int e0   = pair >> 3;
        const int e1   = pair & 7;
        float acc = 0.f;
        #pragma unroll
        for (int r1 = 0; r1 < 8; ++r1)
            acc = fmaf(s0[e0 * 8 + r1], s1[r1 * 64 + e1 * 8 + r2], acc);
        Ar[v] = acc;
    }
}

// ---- Kernel 2: one wave per index; contiguous 1 KB wave stores.
__global__ __launch_bounds__(256) void tt_emb_kernel(
    const int* __restrict__ x,
    const float* __restrict__ A,    // [1024][512]
    const float* __restrict__ c2,   // [32][8][16] = 4096 floats
    float* __restrict__ out,        // [N][1024]
    int N)
{
    __shared__ float s2[4096];      // all of c2, 16 KB
    const int t = threadIdx.x;

    #pragma unroll
    for (int i = 0; i < 4; ++i)
        *reinterpret_cast<float4*>(s2 + (i * 256 + t) * 4) =
            *reinterpret_cast<const float4*>(c2 + (i * 256 + t) * 4);
    __syncthreads();

    const int w = t >> 6;               // wave id 0..3
    const int l = t & 63;               // lane
    const int prow = l >> 2;            // pair sub-index 0..15
    const int eg   = l & 3;             // e2 group (e2 = 4*eg .. +4)
    const int nbase = blockIdx.x * TT_G + w * 4;

    // prefetch this wave's 4 indices in one load (nbase is 16B-aligned)
    const int4 xv = *reinterpret_cast<const int4*>(x + nbase);
    const int flats[4] = {xv.x, xv.y, xv.z, xv.w};

    #pragma unroll 1
    for (int g = 0; g < 4; ++g) {
        const int flat = flats[g];
        const float* Ar  = A + (size_t)((flat >> 5) & 1023) * 512;  // i0*32+i1
        const float* c2s = s2 + (flat & 31) * 128;                  // i2 row

        // A fragments for pairs {prow + 16p}: 8 x b128, issued back-to-back
        float4 alo[4], ahi[4];
        #pragma unroll
        for (int p = 0; p < 4; ++p) {
            const float* ap = Ar + (prow + 16 * p) * 8;
            alo[p] = *reinterpret_cast<const float4*>(ap);
            ahi[p] = *reinterpret_cast<const float4*>(ap + 4);
        }

        // c2 slice for this lane's e2 group: 8 x b128 LDS (shared across p)
        float4 cv[8];
        #pragma unroll
        for (int r2 = 0; r2 < 8; ++r2)
            cv[r2] = *reinterpret_cast<const float4*>(c2s + r2 * 16 + eg * 4);

        float4* outp = reinterpret_cast<float4*>(out + (size_t)(nbase + g) * 1024);
        const bool pad = (flat == 0);

        #pragma unroll
        for (int p = 0; p < 4; ++p) {
            const float ax[8] = {alo[p].x, alo[p].y, alo[p].z, alo[p].w,
                                 ahi[p].x, ahi[p].y, ahi[p].z, ahi[p].w};
            float4 o = make_float4(0.f, 0.f, 0.f, 0.f);
            #pragma unroll
            for (int r2 = 0; r2 < 8; ++r2) {
                o.x = fmaf(ax[r2], cv[r2].x, o.x);
                o.y = fmaf(ax[r2], cv[r2].y, o.y);
                o.z = fmaf(ax[r2], cv[r2].z, o.z);
                o.w = fmaf(ax[r2], cv[r2].w, o.w);
            }
            if (pad) o = make_float4(0.f, 0.f, 0.f, 0.f);   // padding_idx
            outp[l + 64 * p] = o;   // store k=p: contiguous 1 KB per wave
        }
    }
}

// ---- Fallback (ws too small): round-1 LDS kernel, known-good at 39.5 us
__global__ __launch_bounds__(256) void tt_emb_lds_kernel(
    const int* __restrict__ x,
    const float* __restrict__ c0,
    const float* __restrict__ c1,
    const float* __restrict__ c2,
    float* __restrict__ out)
{
    const int n = blockIdx.x;
    const int t = threadIdx.x;

    __shared__ float s0[64];
    __shared__ float s1[512];
    __shared__ float s2[128];

    const int flat = x[n];
    const int i0 = (flat >> 10) & 31;
    const int i1 = (flat >> 5) & 31;
    const int i2 = flat & 31;

    if (t < 64)  s0[t] = c0[i0 * 64 + t];
    s1[t]        = c1[i1 * 512 + t];
    s1[t + 256]  = c1[i1 * 512 + 256 + t];
    if (t < 128) s2[t] = c2[i2 * 128 + t];
    __syncthreads();

    const int e0  = t >> 5;
    const int e1  = (t >> 2) & 7;
    const int e2b = (t & 3) << 2;

    float tmp[8] = {0.f, 0.f, 0.f, 0.f, 0.f, 0.f, 0.f, 0.f};
    #pragma unroll
    for (int r1 = 0; r1 < 8; ++r1) {
        const float a = s0[e0 * 8 + r1];
        #pragma unroll
        for (int r2 = 0; r2 < 8; ++r2)
            tmp[r2] = fmaf(a, s1[r1 * 64 + e1 * 8 + r2], tmp[r2]);
    }

    float res[4];
    #pragma unroll
    for (int q = 0; q < 4; ++q) {
        float acc = 0.f;
        #pragma unroll
        for (int r2 = 0; r2 < 8; ++r2)
            acc = fmaf(tmp[r2], s2[r2 * 16 + e2b + q], acc);
        res[q] = acc;
    }

    if (flat == 0) { res[0] = res[1] = res[2] = res[3] = 0.f; }

    *reinterpret_cast<float4*>(out + (size_t)n * 1024 + (size_t)t * 4) =
        make_float4(res[0], res[1], res[2], res[3]);
}

extern "C" void kernel_launch(void* const* d_in, const int* in_sizes, int n_in,
                              void* d_out, int out_size, void* d_ws, size_t ws_size,
                              hipStream_t stream) {
    const int*   x  = (const int*)d_in[0];     // 32768 indices
    const float* c0 = (const float*)d_in[1];   // 2048 floats
    const float* c1 = (const float*)d_in[2];   // 16384 floats
    const float* c2 = (const float*)d_in[3];   // 4096 floats
    float* out = (float*)d_out;                // 33554432 fp32

    const int N = in_sizes[0];                 // 32768

    if (ws_size >= TT_A_BYTES && (N % TT_G) == 0) {
        float* A = (float*)d_ws;
        tt_precomp_kernel<<<1024, 256, 0, stream>>>(c0, c1, A);
        tt_emb_kernel<<<N / TT_G, 256, 0, stream>>>(x, A, c2, out, N);
    } else {
        tt_emb_lds_kernel<<<N, 256, 0, stream>>>(x, c0, c1, c2, out);
    }
}